// Round 9
// baseline (10989.436 us; speedup 1.0000x reference)
//
#include <hip/hip_runtime.h>

// Problem constants (from reference)
#define SEQ   8192
#define HID   256
#define G3    768      // 3*HID
#define TSTART 1024    // SEQ/8
#define NEGD  1365     // SEQ/6
#define TCNT  5791     // (SEQ - 10 - NEGD - 4 + 2) - TSTART
#define DENOMF 23164.0f // TCNT*4

typedef _Float16 half8 __attribute__((ext_vector_type(8)));
typedef float floatx4 __attribute__((ext_vector_type(4)));

__device__ __forceinline__ float sigmoidf_fast(float x) {
  return 1.0f / (1.0f + __expf(-x));
}
// tanh via sigmoid form: safe at both extremes (exp under/overflow -> +-1)
__device__ __forceinline__ float tanhf_fast(float x) {
  return 2.0f / (1.0f + __expf(-2.0f * x)) - 1.0f;
}

// ---------------------------------------------------------------------------
// init: zero the loss accumulators (ws is poisoned 0xAA every call)
// ---------------------------------------------------------------------------
__global__ void init_kernel(float* accum) {
  if (threadIdx.x < 2) accum[threadIdx.x] = 0.0f;
}

// ---------------------------------------------------------------------------
// wcvt: pre-convert Whh f32 -> f16 packed in MFMA A-fragment order.
// gru wave w owns rows [w*96, w*96+96) as 6 tiles of 16; lane l provides
// A[m=l&15][k=(l>>4)*8+j] (16x16x32 f16 A-layout, guide m120). Fragment
// order per lane: [kc][t] so the K-loop loads contiguously.
// u32 u = ((i*48 + kc*6 + t)*4 + j2) holds halves (k, k+1) of
// row = w*96 + t*16 + m,  k = kc*32 + (l>>4)*8 + j2*2,  i = w*64+l.
// ---------------------------------------------------------------------------
__global__ __launch_bounds__(256) void wcvt_kernel(
    const float* __restrict__ Whh, unsigned* __restrict__ wpkA)
{
  int u = blockIdx.x * 256 + threadIdx.x;    // 0..98303
  int j2   = u & 3;
  int frag = u >> 2;                         // 0..24575
  int t    = frag % 6;
  int kc   = (frag / 6) & 7;
  int gl   = frag / 48;                      // 0..511
  int w    = gl >> 6, l = gl & 63;
  int m    = l & 15, quad = l >> 4;
  int row  = w * 96 + t * 16 + m;
  int k    = kc * 32 + quad * 8 + j2 * 2;
  _Float16 lo = (_Float16)Whh[(size_t)row * 256 + k];
  _Float16 hi = (_Float16)Whh[(size_t)row * 256 + k + 1];
  unsigned v = (unsigned)__builtin_bit_cast(unsigned short, lo) |
               ((unsigned)__builtin_bit_cast(unsigned short, hi) << 16);
  wpkA[u] = v;
}

// ---------------------------------------------------------------------------
// Phase A: xW = data @ Wih^T + bih -> f32 [SEQ][768]. All f32.
// ---------------------------------------------------------------------------
__global__ __launch_bounds__(256) void xw_kernel(
    const float* __restrict__ data, const float* __restrict__ Wih,
    const float* __restrict__ bih, float* __restrict__ xw)
{
  __shared__ float4 xs4[32 * 64];   // 32 rows x 256 f32 = 32 KB
  const int o  = blockIdx.y * 256 + threadIdx.x;
  const int m0 = blockIdx.x * 32;

  float* xsf = (float*)xs4;
  for (int r = 0; r < 32; ++r)
    xsf[r * 256 + threadIdx.x] = data[(size_t)(m0 + r) * 256 + threadIdx.x];
  __syncthreads();

  const float b = bih[o];
  float acc[32];
#pragma unroll
  for (int r = 0; r < 32; ++r) acc[r] = b;

  const float4* wrow = (const float4*)(Wih + (size_t)o * 256);
  for (int kc = 0; kc < 4; ++kc) {
    float4 w[16];
#pragma unroll
    for (int j = 0; j < 16; ++j) w[j] = wrow[kc * 16 + j];
#pragma unroll
    for (int r = 0; r < 32; ++r) {
      const float4* xr = xs4 + r * 64 + kc * 16;
      float a0 = 0.f, a1 = 0.f, a2 = 0.f, a3 = 0.f;
#pragma unroll
      for (int j = 0; j < 4; ++j) {
        float4 x0 = xr[4 * j + 0], x1 = xr[4 * j + 1];
        float4 x2 = xr[4 * j + 2], x3 = xr[4 * j + 3];
        float4 w0 = w[4 * j + 0], w1 = w[4 * j + 1];
        float4 w2 = w[4 * j + 2], w3 = w[4 * j + 3];
        a0 = fmaf(w0.x, x0.x, fmaf(w0.y, x0.y, fmaf(w0.z, x0.z, fmaf(w0.w, x0.w, a0))));
        a1 = fmaf(w1.x, x1.x, fmaf(w1.y, x1.y, fmaf(w1.z, x1.z, fmaf(w1.w, x1.w, a1))));
        a2 = fmaf(w2.x, x2.x, fmaf(w2.y, x2.y, fmaf(w2.z, x2.z, fmaf(w2.w, x2.w, a2))));
        a3 = fmaf(w3.x, x3.x, fmaf(w3.y, x3.y, fmaf(w3.z, x3.z, fmaf(w3.w, x3.w, a3))));
      }
      acc[r] += (a0 + a1) + (a2 + a3);
    }
  }
  for (int r = 0; r < 32; ++r)
    xw[(size_t)(m0 + r) * G3 + o] = acc[r];
}

// ---------------------------------------------------------------------------
// data row norms: one wave per row (f32 data)
// ---------------------------------------------------------------------------
__global__ __launch_bounds__(256) void rnorm_kernel(
    const float* __restrict__ data, float* __restrict__ rn)
{
  int wave = threadIdx.x >> 6, lane = threadIdx.x & 63;
  int row = blockIdx.x * 4 + wave;
  const float* xr = data + (size_t)row * HID;
  float a = xr[lane], b = xr[lane + 64], c = xr[lane + 128], d = xr[lane + 192];
  float s = a * a + b * b + c * c + d * d;
#pragma unroll
  for (int off = 32; off; off >>= 1) s += __shfl_xor(s, off, 64);
  if (lane == 0) rn[row] = fmaxf(sqrtf(s), 1e-8f);
}

// ---------------------------------------------------------------------------
// Phase B: sequential GRU scan via MFMA. ONE block, 512 threads (8 waves,
// 2/SIMD). Wave w owns rows [w*96, w*96+96) of Whh as 6 MFMA A-tiles x 8
// K-chunks = 48 half8 frags/lane (192 regs -- MFMA reads AGPRs natively, so
// the allocator's AGPR placement costs nothing, unlike v_dot2 which needed
// v_accvgpr_read per use = the r4-r8 2x tax). B = h chunk broadcast to all
// 16 columns (one ds_read_b128 per wave per kc -> 64/step vs 384 before);
// D columns all equal. Epilogue: one ds_write_b128 per wave. Gate math on
// threads i<256 (waves 0-3), h in LDS f16, 2 barriers/step.
// ---------------------------------------------------------------------------
__global__ __launch_bounds__(512, 2) void gru_kernel(
    const unsigned* __restrict__ wpkA, const float* __restrict__ bhh,
    const float* __restrict__ xw, float* __restrict__ zout)
{
  __shared__ __align__(16) _Float16 hpk[256];   // h as f16
  __shared__ __align__(16) float preAll[G3];    // pre-activations, row-major
  const int i = threadIdx.x;
  const int w = i >> 6, lane = i & 63;
  const int col = lane & 15, quad = lane >> 4;
  const bool isGate = (i < 256);

  // --- weights: 48 A-fragments straight into final registers ---
  half8 wA[48];
  {
    const half8* wp = (const half8*)wpkA + (size_t)i * 48;
#pragma unroll
    for (int j = 0; j < 48; ++j) wA[j] = wp[j];
  }
  float br = 0.f, bz = 0.f, bn = 0.f, hreg = 0.0f;
  float xr0 = 0.f, xz0 = 0.f, xn0 = 0.f;
  if (isGate) {
    br = bhh[i]; bz = bhh[256 + i]; bn = bhh[512 + i];
    xr0 = xw[i]; xz0 = xw[256 + i]; xn0 = xw[512 + i];
    hpk[i] = (_Float16)0.0f;
  }
  __syncthreads();

  for (int s = 0; s < SEQ; ++s) {
    // prefetch next step's xw (gate waves only; latency hidden by MFMA)
    float nr = 0.f, nz = 0.f, nn = 0.f;
    if (isGate) {
      const size_t bnext = (size_t)(s + 1 < SEQ ? s + 1 : s) * G3;
      nr = xw[bnext + i]; nz = xw[bnext + 256 + i]; nn = xw[bnext + 512 + i];
    }

    // --- y = Whh_f16 * h via MFMA: 8 K-chunks x 6 tiles ---
    floatx4 acc[6];
#pragma unroll
    for (int t = 0; t < 6; ++t) acc[t] = (floatx4){0.f, 0.f, 0.f, 0.f};
#pragma unroll
    for (int kc = 0; kc < 8; ++kc) {
      // B frag: h[kc*32 + quad*8 .. +8), same for all 16 columns
      half8 hb = *(const half8*)((const char*)hpk + kc * 64 + quad * 16);
#pragma unroll
      for (int t = 0; t < 6; ++t)
        acc[t] = __builtin_amdgcn_mfma_f32_16x16x32_f16(wA[kc * 6 + t], hb,
                                                        acc[t], 0, 0, 0);
    }

    // --- epilogue: lane with col==t writes tile t's 4 rows (one b128) ---
    float p0 = col == 0 ? acc[0][0] : col == 1 ? acc[1][0] : col == 2 ? acc[2][0]
             : col == 3 ? acc[3][0] : col == 4 ? acc[4][0] : acc[5][0];
    float p1 = col == 0 ? acc[0][1] : col == 1 ? acc[1][1] : col == 2 ? acc[2][1]
             : col == 3 ? acc[3][1] : col == 4 ? acc[4][1] : acc[5][1];
    float p2 = col == 0 ? acc[0][2] : col == 1 ? acc[1][2] : col == 2 ? acc[2][2]
             : col == 3 ? acc[3][2] : col == 4 ? acc[4][2] : acc[5][2];
    float p3 = col == 0 ? acc[0][3] : col == 1 ? acc[1][3] : col == 2 ? acc[2][3]
             : col == 3 ? acc[3][3] : col == 4 ? acc[4][3] : acc[5][3];
    if (col < 6) {
      // D row = quad*4 + reg (m89 C/D layout); global row = w*96+col*16+row
      float4* dst = (float4*)&preAll[w * 96 + col * 16 + quad * 4];
      *dst = make_float4(p0, p1, p2, p3);
    }
    __syncthreads();

    // --- gate math on waves 0-3 (wave-uniform branch) ---
    if (isGate) {
      float rg = sigmoidf_fast(preAll[i] + br + xr0);
      float zg = sigmoidf_fast(preAll[256 + i] + bz + xz0);
      float ng = tanhf_fast(xn0 + rg * (preAll[512 + i] + bn));
      hreg = (1.0f - zg) * ng + zg * hreg;
      hpk[i] = (_Float16)hreg;
      zout[(size_t)s * HID + i] = hreg;
    }
    __syncthreads();
    xr0 = nr; xz0 = nz; xn0 = nn;
  }
}

// ---------------------------------------------------------------------------
// Phase C: NCE loss + accuracy. One block per t, 4 waves = 4 timespans.
// Reads f32 z straight from d_out.
// ---------------------------------------------------------------------------
__global__ __launch_bounds__(256) void cpc_kernel(
    const float* __restrict__ x, const float* __restrict__ zf,
    const float* __restrict__ rn, float* __restrict__ accum)
{
  __shared__ float zsh[HID];
  __shared__ float wsum[4];
  __shared__ float nce_s[4], acc_s[4];
  const int tt = TSTART + blockIdx.x;
  const int i = threadIdx.x;
  const int wave = i >> 6, lane = i & 63;

  float zi = zf[(size_t)tt * HID + i];
  zsh[i] = zi;
  float p = zi * zi;
#pragma unroll
  for (int off = 32; off; off >>= 1) p += __shfl_xor(p, off, 64);
  if (lane == 0) wsum[wave] = p;
  __syncthreads();
  float zn = fmaxf(sqrtf(wsum[0] + wsum[1] + wsum[2] + wsum[3]), 1e-8f);

  float z0 = zsh[lane], z1 = zsh[lane + 64], z2 = zsh[lane + 128], z3 = zsh[lane + 192];
  const int base = tt + wave + 1;   // pos index for timespan (wave+1)

  float tot[10];
#pragma unroll
  for (int n = 0; n < 10; ++n) {
    int idx = base + (n > 0 ? (NEGD + n - 1) : 0);
    const float* xr = x + (size_t)idx * HID;
    float q = xr[lane] * z0 + xr[lane + 64] * z1 + xr[lane + 128] * z2 + xr[lane + 192] * z3;
#pragma unroll
    for (int off = 32; off; off >>= 1) q += __shfl_xor(q, off, 64);
    tot[n] = q / (rn[idx] * zn);
  }
  float m = tot[0];
#pragma unroll
  for (int n = 1; n < 10; ++n) m = fmaxf(m, tot[n]);
  float se = 0.f;
#pragma unroll
  for (int n = 0; n < 10; ++n) se += expf(tot[n] - m);
  float logp0 = (tot[0] - m) - logf(se);
  float accv = (tot[0] >= m) ? 1.0f : 0.0f;  // argmax==0 iff tot[0] is the max

  if (lane == 0) { nce_s[wave] = -logp0; acc_s[wave] = accv; }
  __syncthreads();
  if (i == 0) {
    atomicAdd(accum,     nce_s[0] + nce_s[1] + nce_s[2] + nce_s[3]);
    atomicAdd(accum + 1, acc_s[0] + acc_s[1] + acc_s[2] + acc_s[3]);
  }
}

__global__ void fin_kernel(const float* __restrict__ accum,
                           float* __restrict__ out)
{
  if (threadIdx.x == 0) {
    out[(size_t)SEQ * HID]     = accum[0] / DENOMF;   // nce
    out[(size_t)SEQ * HID + 1] = accum[1] / DENOMF;   // acc
  }
}

// ---------------------------------------------------------------------------
extern "C" void kernel_launch(void* const* d_in, const int* in_sizes, int n_in,
                              void* d_out, int out_size, void* d_ws, size_t ws_size,
                              hipStream_t stream)
{
  // Inputs are f32 (reference dtypes). Output f32: z [SEQ*HID] | nce | acc.
  const float* data = (const float*)d_in[0];
  const float* Wih  = (const float*)d_in[1];
  const float* Whh  = (const float*)d_in[2];
  const float* bih  = (const float*)d_in[3];
  const float* bhh  = (const float*)d_in[4];
  float* out = (float*)d_out;

  // ws layout: xw f32 [SEQ*768] 25.17MB | wpkA u32 [98304] 393KB |
  //            rn f32 [SEQ] | accum f32 [2]
  char* p = (char*)d_ws;
  float*    xw    = (float*)p;     p += (size_t)SEQ * G3 * sizeof(float);
  unsigned* wpkA  = (unsigned*)p;  p += (size_t)98304 * sizeof(unsigned);
  float*    rn    = (float*)p;     p += (size_t)SEQ * sizeof(float);
  float*    accum = (float*)p;

  init_kernel<<<1, 64, 0, stream>>>(accum);
  wcvt_kernel<<<384, 256, 0, stream>>>(Whh, wpkA);
  xw_kernel<<<dim3(256, 3), 256, 0, stream>>>(data, Wih, bih, xw);
  rnorm_kernel<<<SEQ / 4, 256, 0, stream>>>(data, rn);
  gru_kernel<<<1, 512, 0, stream>>>(wpkA, bhh, xw, out);
  cpc_kernel<<<TCNT, 256, 0, stream>>>(data, out, rn, accum);
  fin_kernel<<<1, 1, 0, stream>>>(accum, out);
}

// Round 10
// 10447.813 us; speedup vs baseline: 1.0518x; 1.0518x over previous
//
#include <hip/hip_runtime.h>

// Problem constants (from reference)
#define SEQ   8192
#define HID   256
#define G3    768      // 3*HID
#define TSTART 1024    // SEQ/8
#define NEGD  1365     // SEQ/6
#define TCNT  5791     // (SEQ - 10 - NEGD - 4 + 2) - TSTART
#define DENOMF 23164.0f // TCNT*4

typedef _Float16 half8 __attribute__((ext_vector_type(8)));
typedef float floatx4 __attribute__((ext_vector_type(4)));

__device__ __forceinline__ float sigmoidf_fast(float x) {
  return 1.0f / (1.0f + __expf(-x));
}
// tanh via sigmoid form: safe at both extremes (exp under/overflow -> +-1)
__device__ __forceinline__ float tanhf_fast(float x) {
  return 2.0f / (1.0f + __expf(-2.0f * x)) - 1.0f;
}

// ---------------------------------------------------------------------------
// init: zero the loss accumulators (ws is poisoned 0xAA every call)
// ---------------------------------------------------------------------------
__global__ void init_kernel(float* accum) {
  if (threadIdx.x < 2) accum[threadIdx.x] = 0.0f;
}

// ---------------------------------------------------------------------------
// wcvt: pre-convert Whh f32 -> f16 packed in MFMA A-fragment order.
// gru wave w owns rows [w*96, w*96+96) as 6 tiles of 16; lane l provides
// A[m=l&15][k=(l>>4)*8+j] (16x16x32 f16 A-layout). Fragment order per lane:
// [kc][t] so the K-loop loads contiguously.
// ---------------------------------------------------------------------------
__global__ __launch_bounds__(256) void wcvt_kernel(
    const float* __restrict__ Whh, unsigned* __restrict__ wpkA)
{
  int u = blockIdx.x * 256 + threadIdx.x;    // 0..98303
  int j2   = u & 3;
  int frag = u >> 2;                         // 0..24575
  int t    = frag % 6;
  int kc   = (frag / 6) & 7;
  int gl   = frag / 48;                      // 0..511
  int w    = gl >> 6, l = gl & 63;
  int m    = l & 15, quad = l >> 4;
  int row  = w * 96 + t * 16 + m;
  int k    = kc * 32 + quad * 8 + j2 * 2;
  _Float16 lo = (_Float16)Whh[(size_t)row * 256 + k];
  _Float16 hi = (_Float16)Whh[(size_t)row * 256 + k + 1];
  unsigned v = (unsigned)__builtin_bit_cast(unsigned short, lo) |
               ((unsigned)__builtin_bit_cast(unsigned short, hi) << 16);
  wpkA[u] = v;
}

// ---------------------------------------------------------------------------
// Phase A: xW = data @ Wih^T + bih -> f32 [SEQ][768]. All f32.
// ---------------------------------------------------------------------------
__global__ __launch_bounds__(256) void xw_kernel(
    const float* __restrict__ data, const float* __restrict__ Wih,
    const float* __restrict__ bih, float* __restrict__ xw)
{
  __shared__ float4 xs4[32 * 64];   // 32 rows x 256 f32 = 32 KB
  const int o  = blockIdx.y * 256 + threadIdx.x;
  const int m0 = blockIdx.x * 32;

  float* xsf = (float*)xs4;
  for (int r = 0; r < 32; ++r)
    xsf[r * 256 + threadIdx.x] = data[(size_t)(m0 + r) * 256 + threadIdx.x];
  __syncthreads();

  const float b = bih[o];
  float acc[32];
#pragma unroll
  for (int r = 0; r < 32; ++r) acc[r] = b;

  const float4* wrow = (const float4*)(Wih + (size_t)o * 256);
  for (int kc = 0; kc < 4; ++kc) {
    float4 w[16];
#pragma unroll
    for (int j = 0; j < 16; ++j) w[j] = wrow[kc * 16 + j];
#pragma unroll
    for (int r = 0; r < 32; ++r) {
      const float4* xr = xs4 + r * 64 + kc * 16;
      float a0 = 0.f, a1 = 0.f, a2 = 0.f, a3 = 0.f;
#pragma unroll
      for (int j = 0; j < 4; ++j) {
        float4 x0 = xr[4 * j + 0], x1 = xr[4 * j + 1];
        float4 x2 = xr[4 * j + 2], x3 = xr[4 * j + 3];
        float4 w0 = w[4 * j + 0], w1 = w[4 * j + 1];
        float4 w2 = w[4 * j + 2], w3 = w[4 * j + 3];
        a0 = fmaf(w0.x, x0.x, fmaf(w0.y, x0.y, fmaf(w0.z, x0.z, fmaf(w0.w, x0.w, a0))));
        a1 = fmaf(w1.x, x1.x, fmaf(w1.y, x1.y, fmaf(w1.z, x1.z, fmaf(w1.w, x1.w, a1))));
        a2 = fmaf(w2.x, x2.x, fmaf(w2.y, x2.y, fmaf(w2.z, x2.z, fmaf(w2.w, x2.w, a2))));
        a3 = fmaf(w3.x, x3.x, fmaf(w3.y, x3.y, fmaf(w3.z, x3.z, fmaf(w3.w, x3.w, a3))));
      }
      acc[r] += (a0 + a1) + (a2 + a3);
    }
  }
  for (int r = 0; r < 32; ++r)
    xw[(size_t)(m0 + r) * G3 + o] = acc[r];
}

// ---------------------------------------------------------------------------
// data row norms: one wave per row (f32 data)
// ---------------------------------------------------------------------------
__global__ __launch_bounds__(256) void rnorm_kernel(
    const float* __restrict__ data, float* __restrict__ rn)
{
  int wave = threadIdx.x >> 6, lane = threadIdx.x & 63;
  int row = blockIdx.x * 4 + wave;
  const float* xr = data + (size_t)row * HID;
  float a = xr[lane], b = xr[lane + 64], c = xr[lane + 128], d = xr[lane + 192];
  float s = a * a + b * b + c * c + d * d;
#pragma unroll
  for (int off = 32; off; off >>= 1) s += __shfl_xor(s, off, 64);
  if (lane == 0) rn[row] = fmaxf(sqrtf(s), 1e-8f);
}

// ---------------------------------------------------------------------------
// Phase B: sequential GRU scan via MFMA. ONE block, 512 threads (8 waves,
// 2/SIMD). Wave w owns rows [w*96,+96) as 6 A-tiles x 8 K-chunks (48 half8
// frags). R9 lesson: per-kc ds_read -> lgkmcnt(0) -> MFMA serialized 8 LDS
// latencies (~1200 cyc); now a DEPTH-2 PREFETCH RING overlaps hb(kc+1) load
// with kc's 6 MFMAs. Epilogue: 6 exec-masked float4 stores (no cndmask
// chains, conflict-free banks). Gate math on waves 0-3; 2 barriers/step.
// ---------------------------------------------------------------------------
__global__ __launch_bounds__(512, 2) void gru_kernel(
    const unsigned* __restrict__ wpkA, const float* __restrict__ bhh,
    const float* __restrict__ xw, float* __restrict__ zout)
{
  __shared__ __align__(16) _Float16 hpk[256];   // h as f16
  __shared__ __align__(16) float preAll[G3];    // pre-activations, row-major
  const int i = threadIdx.x;
  const int w = i >> 6, lane = i & 63;
  const int col = lane & 15, quad = lane >> 4;
  const bool isGate = (i < 256);

  // --- weights: 48 A-fragments straight into final registers ---
  half8 wA[48];
  {
    const half8* wp = (const half8*)wpkA + (size_t)i * 48;
#pragma unroll
    for (int j = 0; j < 48; ++j) wA[j] = wp[j];
  }
  float br = 0.f, bz = 0.f, bn = 0.f, hreg = 0.0f;
  float xr0 = 0.f, xz0 = 0.f, xn0 = 0.f;
  if (isGate) {
    br = bhh[i]; bz = bhh[256 + i]; bn = bhh[512 + i];
    xr0 = xw[i]; xz0 = xw[256 + i]; xn0 = xw[512 + i];
    hpk[i] = (_Float16)0.0f;
  }
  __syncthreads();

  for (int s = 0; s < SEQ; ++s) {
    // prefetch next step's xw (gate waves only; latency hidden by MFMA)
    float nr = 0.f, nz = 0.f, nn = 0.f;
    if (isGate) {
      const size_t bnext = (size_t)(s + 1 < SEQ ? s + 1 : s) * G3;
      nr = xw[bnext + i]; nz = xw[bnext + 256 + i]; nn = xw[bnext + 512 + i];
    }

    // --- y = Whh_f16 * h via MFMA, depth-2 hb prefetch ring ---
    const char* hbase = (const char*)hpk + quad * 16;
    half8 hb = *(const half8*)(hbase);            // kc = 0
    floatx4 acc[6];
#pragma unroll
    for (int t = 0; t < 6; ++t) acc[t] = (floatx4){0.f, 0.f, 0.f, 0.f};
#pragma unroll
    for (int kc = 0; kc < 8; ++kc) {
      half8 hb_n = (kc < 7) ? *(const half8*)(hbase + (kc + 1) * 64) : hb;
#pragma unroll
      for (int t = 0; t < 6; ++t)
        acc[t] = __builtin_amdgcn_mfma_f32_16x16x32_f16(wA[kc * 6 + t], hb,
                                                        acc[t], 0, 0, 0);
      hb = hb_n;
    }

    // --- epilogue: exec-masked stores; lane col==t writes tile t's 4 rows ---
#pragma unroll
    for (int t = 0; t < 6; ++t) {
      if (col == t) {
        float4* dst = (float4*)&preAll[w * 96 + t * 16 + quad * 4];
        *dst = make_float4(acc[t][0], acc[t][1], acc[t][2], acc[t][3]);
      }
    }
    __syncthreads();

    // --- gate math on waves 0-3 (wave-uniform branch) ---
    if (isGate) {
      float rg = sigmoidf_fast(preAll[i] + br + xr0);
      float zg = sigmoidf_fast(preAll[256 + i] + bz + xz0);
      float ng = tanhf_fast(xn0 + rg * (preAll[512 + i] + bn));
      hreg = (1.0f - zg) * ng + zg * hreg;
      hpk[i] = (_Float16)hreg;
      zout[(size_t)s * HID + i] = hreg;
    }
    __syncthreads();
    xr0 = nr; xz0 = nz; xn0 = nn;
  }
}

// ---------------------------------------------------------------------------
// Phase C: NCE loss + accuracy. One block per t, 4 waves = 4 timespans.
// Reads f32 z straight from d_out.
// ---------------------------------------------------------------------------
__global__ __launch_bounds__(256) void cpc_kernel(
    const float* __restrict__ x, const float* __restrict__ zf,
    const float* __restrict__ rn, float* __restrict__ accum)
{
  __shared__ float zsh[HID];
  __shared__ float wsum[4];
  __shared__ float nce_s[4], acc_s[4];
  const int tt = TSTART + blockIdx.x;
  const int i = threadIdx.x;
  const int wave = i >> 6, lane = i & 63;

  float zi = zf[(size_t)tt * HID + i];
  zsh[i] = zi;
  float p = zi * zi;
#pragma unroll
  for (int off = 32; off; off >>= 1) p += __shfl_xor(p, off, 64);
  if (lane == 0) wsum[wave] = p;
  __syncthreads();
  float zn = fmaxf(sqrtf(wsum[0] + wsum[1] + wsum[2] + wsum[3]), 1e-8f);

  float z0 = zsh[lane], z1 = zsh[lane + 64], z2 = zsh[lane + 128], z3 = zsh[lane + 192];
  const int base = tt + wave + 1;   // pos index for timespan (wave+1)

  float tot[10];
#pragma unroll
  for (int n = 0; n < 10; ++n) {
    int idx = base + (n > 0 ? (NEGD + n - 1) : 0);
    const float* xr = x + (size_t)idx * HID;
    float q = xr[lane] * z0 + xr[lane + 64] * z1 + xr[lane + 128] * z2 + xr[lane + 192] * z3;
#pragma unroll
    for (int off = 32; off; off >>= 1) q += __shfl_xor(q, off, 64);
    tot[n] = q / (rn[idx] * zn);
  }
  float m = tot[0];
#pragma unroll
  for (int n = 1; n < 10; ++n) m = fmaxf(m, tot[n]);
  float se = 0.f;
#pragma unroll
  for (int n = 0; n < 10; ++n) se += expf(tot[n] - m);
  float logp0 = (tot[0] - m) - logf(se);
  float accv = (tot[0] >= m) ? 1.0f : 0.0f;  // argmax==0 iff tot[0] is the max

  if (lane == 0) { nce_s[wave] = -logp0; acc_s[wave] = accv; }
  __syncthreads();
  if (i == 0) {
    atomicAdd(accum,     nce_s[0] + nce_s[1] + nce_s[2] + nce_s[3]);
    atomicAdd(accum + 1, acc_s[0] + acc_s[1] + acc_s[2] + acc_s[3]);
  }
}

__global__ void fin_kernel(const float* __restrict__ accum,
                           float* __restrict__ out)
{
  if (threadIdx.x == 0) {
    out[(size_t)SEQ * HID]     = accum[0] / DENOMF;   // nce
    out[(size_t)SEQ * HID + 1] = accum[1] / DENOMF;   // acc
  }
}

// ---------------------------------------------------------------------------
extern "C" void kernel_launch(void* const* d_in, const int* in_sizes, int n_in,
                              void* d_out, int out_size, void* d_ws, size_t ws_size,
                              hipStream_t stream)
{
  // Inputs are f32 (reference dtypes). Output f32: z [SEQ*HID] | nce | acc.
  const float* data = (const float*)d_in[0];
  const float* Wih  = (const float*)d_in[1];
  const float* Whh  = (const float*)d_in[2];
  const float* bih  = (const float*)d_in[3];
  const float* bhh  = (const float*)d_in[4];
  float* out = (float*)d_out;

  // ws layout: xw f32 [SEQ*768] 25.17MB | wpkA u32 [98304] 393KB |
  //            rn f32 [SEQ] | accum f32 [2]
  char* p = (char*)d_ws;
  float*    xw    = (float*)p;     p += (size_t)SEQ * G3 * sizeof(float);
  unsigned* wpkA  = (unsigned*)p;  p += (size_t)98304 * sizeof(unsigned);
  float*    rn    = (float*)p;     p += (size_t)SEQ * sizeof(float);
  float*    accum = (float*)p;

  init_kernel<<<1, 64, 0, stream>>>(accum);
  wcvt_kernel<<<384, 256, 0, stream>>>(Whh, wpkA);
  xw_kernel<<<dim3(256, 3), 256, 0, stream>>>(data, Wih, bih, xw);
  rnorm_kernel<<<SEQ / 4, 256, 0, stream>>>(data, rn);
  gru_kernel<<<1, 512, 0, stream>>>(wpkA, bhh, xw, out);
  cpc_kernel<<<TCNT, 256, 0, stream>>>(data, out, rn, accum);
  fin_kernel<<<1, 1, 0, stream>>>(accum, out);
}